// Round 9
// baseline (234.558 us; speedup 1.0000x reference)
//
#include <hip/hip_runtime.h>
#include <stdint.h>

// Problem constants
#define BB 8
#define DD 256
#define NN 2048
#define HH 4
#define HD 64
// 0.125 (1/sqrt(64)) * log2(e): puts scores in log2-domain so P = exp2(S)
#define SCALE_Q 0.18033688011112042f

typedef __attribute__((ext_vector_type(8))) short bf16x8;   // 8 bf16 = 4 VGPRs
typedef __attribute__((ext_vector_type(4))) float f32x4;
typedef __attribute__((ext_vector_type(16))) float f32x16;
typedef __attribute__((ext_vector_type(4))) unsigned short u16x4;

// ---- helpers --------------------------------------------------------------

__device__ __forceinline__ void gld16(const void* g, void* l) {
  // async global->LDS, 16B per lane; LDS dest = wave-uniform base + lane*16
  __builtin_amdgcn_global_load_lds(
      (__attribute__((address_space(1))) void*)(void*)(uintptr_t)(g),
      (__attribute__((address_space(3))) void*)(l), 16, 0, 0);
}

__device__ __forceinline__ unsigned short f2bf(float f) {
  union { float f; unsigned u; } v; v.f = f;
  unsigned lsb = (v.u >> 16) & 1u;
  v.u += 0x7fffu + lsb;               // RNE
  return (unsigned short)(v.u >> 16);
}

// ---- X transpose+cast: fp32 [B][D][N] -> bf16 [B][N][D], 64x64, vectorized
// float4 loads (16B/lane), LDS fp32 staging, ushort4 stores (8B/lane).

__global__ __launch_bounds__(256) void tcast_x(
    const float* __restrict__ q, const float* __restrict__ k,
    const float* __restrict__ v, unsigned short* __restrict__ oq,
    unsigned short* __restrict__ ok2, unsigned short* __restrict__ ov) {
  __shared__ float t[64][65];
  int z = blockIdx.z, src = z >> 3, b = z & 7;
  const float* ip = (src == 0 ? q : src == 1 ? k : v) + (long)b * DD * NN;
  unsigned short* op = (src == 0 ? oq : src == 1 ? ok2 : ov) + (long)b * NN * DD;
  int c0 = blockIdx.x * 64, r0 = blockIdx.y * 64;  // c0: n, r0: d
  int id = threadIdx.x;
  int hi4 = id >> 4, lo4 = id & 15;
#pragma unroll
  for (int r = 0; r < 4; r++) {
    int d = r * 16 + hi4;
    float4 vv = *(const float4*)(ip + (long)(r0 + d) * NN + c0 + lo4 * 4);
    t[d][lo4 * 4 + 0] = vv.x;
    t[d][lo4 * 4 + 1] = vv.y;
    t[d][lo4 * 4 + 2] = vv.z;
    t[d][lo4 * 4 + 3] = vv.w;
  }
  __syncthreads();
#pragma unroll
  for (int rr = 0; rr < 4; rr++) {
    int n = rr * 16 + hi4;
    u16x4 o4;
#pragma unroll
    for (int j = 0; j < 4; j++) o4[j] = f2bf(t[lo4 * 4 + j][n]);
    *(u16x4*)(op + (long)(c0 + n) * DD + r0 + lo4 * 4) = o4;
  }
}

// ---- W transpose+cast with head permutation -------------------------------
// z<3 (Wq/Wk/Wv): out[j'][d] = s*W[d][o], j' = h*64+hd where o = hd*4+h
// z=3 (Wm):       out[o2][k'] = W[p(k')][o2]  (k-dim permuted to match XA)

__global__ __launch_bounds__(256) void tcast_w(
    const float* __restrict__ Wq, const float* __restrict__ Wk,
    const float* __restrict__ Wv, const float* __restrict__ Wm,
    unsigned short* __restrict__ oWq, unsigned short* __restrict__ oWk,
    unsigned short* __restrict__ oWv, unsigned short* __restrict__ oWm) {
  __shared__ float t[32][33];
  int z = blockIdx.z;
  const float* ip = z == 0 ? Wq : z == 1 ? Wk : z == 2 ? Wv : Wm;
  unsigned short* op = z == 0 ? oWq : z == 1 ? oWk : z == 2 ? oWv : oWm;
  float s = z == 0 ? SCALE_Q : 1.f;
  int c0 = blockIdx.x * 32, r0 = blockIdx.y * 32;
  int tx = threadIdx.x & 31, ty = threadIdx.x >> 5;
#pragma unroll
  for (int rr = 0; rr < 4; rr++) {
    int r = rr * 8 + ty;
    t[r][tx] = ip[(long)(r0 + r) * DD + c0 + tx];
  }
  __syncthreads();
  if (z < 3) {
#pragma unroll
    for (int rr = 0; rr < 4; rr++) {
      int c = rr * 8 + ty;
      int o = c0 + c;
      int jp = ((o & 3) << 6) | (o >> 2);   // inv_p: o=hd*4+h -> j'=h*64+hd
      op[(long)jp * DD + r0 + tx] = f2bf(s * t[tx][c]);
    }
  } else {
#pragma unroll
    for (int rr = 0; rr < 4; rr++) {
      int c = rr * 8 + ty;
      int d = r0 + tx;
      int kp = ((d & 3) << 6) | (d >> 2);
      op[(long)(c0 + c) * DD + kp] = f2bf(t[tx][c]);
    }
  }
}

// ---- shared GEMM core: 128(i) x 64(j) tile, K=256, 2-phase pipelined ------

#define GEMM_STAGE(kt, buf)                                                    \
  {                                                                            \
    int _kt = (kt);                                                            \
    _Pragma("unroll") for (int c = 0; c < 4; c++) {                            \
      int row = w * 32 + c * 8 + (lane >> 3);                                  \
      int so = ((lane & 7) * 16) ^ ((row & 7) << 4);                           \
      gld16((const char*)Ag + ((long)(i0 + row) * DD + _kt * 64) * 2 + so,     \
            (char*)&At[buf][0] + (w * 32 + c * 8) * 128);                      \
    }                                                                          \
    _Pragma("unroll") for (int c = 0; c < 2; c++) {                            \
      int row = w * 16 + c * 8 + (lane >> 3);                                  \
      int so = ((lane & 7) * 16) ^ ((row & 7) << 4);                           \
      gld16((const char*)Bg + ((long)(j0 + row) * DD + _kt * 64) * 2 + so,     \
            (char*)&Bt[buf][0] + (w * 16 + c * 8) * 128);                      \
    }                                                                          \
  }

#define GEMM_COMPUTE(buf)                                                      \
  _Pragma("unroll") for (int ks = 0; ks < 2; ks++) {                           \
    bf16x8 af[4], bfv[2];                                                      \
    _Pragma("unroll") for (int mi = 0; mi < 4; mi++) {                         \
      int row = wr * 64 + mi * 16 + (lane & 15);                               \
      int off = (ks * 64 + (lane >> 4) * 16) ^ ((row & 7) << 4);               \
      af[mi] = *(const bf16x8*)((const char*)&At[buf][0] + row * 128 + off);   \
    }                                                                          \
    _Pragma("unroll") for (int nj = 0; nj < 2; nj++) {                         \
      int row = wc * 32 + nj * 16 + (lane & 15);                               \
      int off = (ks * 64 + (lane >> 4) * 16) ^ ((row & 7) << 4);               \
      bfv[nj] = *(const bf16x8*)((const char*)&Bt[buf][0] + row * 128 + off);  \
    }                                                                          \
    _Pragma("unroll") for (int mi = 0; mi < 4; mi++)                           \
        _Pragma("unroll") for (int nj = 0; nj < 2; nj++)                       \
            acc[mi][nj] = __builtin_amdgcn_mfma_f32_16x16x32_bf16(             \
                af[mi], bfv[nj], acc[mi][nj], 0, 0, 0);                        \
  }

#define GEMM_MAIN()                                                            \
  f32x4 acc[4][2];                                                             \
  _Pragma("unroll") for (int a = 0; a < 4; a++)                                \
      _Pragma("unroll") for (int c = 0; c < 2; c++)                            \
          acc[a][c] = (f32x4){0.f, 0.f, 0.f, 0.f};                             \
  GEMM_STAGE(0, 0);                                                            \
  __syncthreads();                                                             \
  int buf = 0;                                                                 \
  for (int kt = 0; kt < 4; kt++) {                                             \
    if (kt < 3) GEMM_STAGE(kt + 1, buf ^ 1);                                   \
    GEMM_COMPUTE(buf);                                                         \
    __syncthreads();                                                           \
    buf ^= 1;                                                                  \
  }

// ---- fused QKV projection GEMM --------------------------------------------
// proj 0/1: C[n][j'=h*64+hd] -> Qh/Kh [b][h][n][hd]
// proj 2:   C[i'=h*64+hd][m] -> Vh [b][h][hd][m]

__global__ __launch_bounds__(256) void gemm_qkv(
    const unsigned short* __restrict__ Xq, const unsigned short* __restrict__ Xk,
    const unsigned short* __restrict__ Xv, const unsigned short* __restrict__ Wq,
    const unsigned short* __restrict__ Wk, const unsigned short* __restrict__ Wv,
    const float* __restrict__ bq, const float* __restrict__ bk,
    const float* __restrict__ bv, unsigned short* __restrict__ Qh,
    unsigned short* __restrict__ Kh, unsigned short* __restrict__ Vh) {
  __shared__ unsigned short At[2][128 * 64], Bt[2][64 * 64];
  int z = blockIdx.z, proj = z >> 3, bb = z & 7;
  int flat = blockIdx.y * 16 + blockIdx.x;  // 0..63
  const unsigned short *Ag, *Bg;
  const float* bias;
  float bsc = 1.f;
  int i0, j0;
  if (proj == 0) {
    Ag = Xq + (long)bb * NN * DD; Bg = Wq; bias = bq; bsc = SCALE_Q;
    i0 = (flat & 15) * 128; j0 = (flat >> 4) * 64;
  } else if (proj == 1) {
    Ag = Xk + (long)bb * NN * DD; Bg = Wk; bias = bk;
    i0 = (flat & 15) * 128; j0 = (flat >> 4) * 64;
  } else {
    Ag = Wv; Bg = Xv + (long)bb * NN * DD; bias = bv;
    i0 = (flat >> 5) * 128; j0 = (flat & 31) * 64;
  }
  int tid = threadIdx.x, lane = tid & 63, w = tid >> 6;
  int wr = w >> 1, wc = w & 1;

  GEMM_MAIN();

#pragma unroll
  for (int mi = 0; mi < 4; mi++) {
#pragma unroll
    for (int nj = 0; nj < 2; nj++) {
#pragma unroll
      for (int r = 0; r < 4; r++) {
        int ig = i0 + wr * 64 + mi * 16 + (lane >> 4) * 4 + r;
        int jg = j0 + wc * 32 + nj * 16 + (lane & 15);
        float v = acc[mi][nj][r];
        if (proj < 2) {
          int o = ((jg & 63) << 2) | (jg >> 6);
          v += bias[o] * bsc;
          int hh = jg >> 6, hd = jg & 63;
          unsigned short* dst = proj == 0 ? Qh : Kh;
          dst[(((long)bb * HH + hh) * NN + ig) * HD + hd] = f2bf(v);
        } else {
          int o = ((ig & 63) << 2) | (ig >> 6);
          v += bias[o];
          int hh = ig >> 6, hd = ig & 63;
          Vh[(((long)bb * HH + hh) * HD + hd) * NN + jg] = f2bf(v);
        }
      }
    }
  }
}

// ---- output projection: C[o2][n] = sum_k Wmt[o2][k]*XA[n][k] + bm ---------

__global__ __launch_bounds__(256) void gemm_out(
    const unsigned short* __restrict__ A, const unsigned short* __restrict__ B,
    const float* __restrict__ bias, float* __restrict__ out) {
  __shared__ unsigned short At[2][128 * 64], Bt[2][64 * 64];
  int bb = blockIdx.z;
  int flat = blockIdx.y * 16 + blockIdx.x;
  const unsigned short* Ag = A;
  const unsigned short* Bg = B + (long)bb * NN * DD;
  int i0 = (flat >> 5) * 128, j0 = (flat & 31) * 64;
  int tid = threadIdx.x, lane = tid & 63, w = tid >> 6;
  int wr = w >> 1, wc = w & 1;

  GEMM_MAIN();

#pragma unroll
  for (int mi = 0; mi < 4; mi++) {
#pragma unroll
    for (int nj = 0; nj < 2; nj++) {
#pragma unroll
      for (int r = 0; r < 4; r++) {
        int ig = i0 + wr * 64 + mi * 16 + (lane >> 4) * 4 + r;
        int jg = j0 + wc * 32 + nj * 16 + (lane & 15);
        out[((long)bb * DD + ig) * NN + jg] = acc[mi][nj][r] + bias[ig];
      }
    }
  }
}

// ---- flash attention, swapped-QK^T 32x32, intra-block KV-split x2 ---------
// 8 waves (512 thr): waves 0-3 = q-sets over KV[0,1024), waves 4-7 over
// KV[1024,2048). 2-tile unrolled loop w/ compile-time buffer index (ds offset
// folding); vf reads hoisted above exp2/pack (latency shadow); T5 setprio
// around MFMA clusters. m==0 softmax; P->A-frags via cvt_pk+permlane32_swap.

#define ATTN_TILE(CUR)                                                         \
  _Pragma("unroll") for (int kh = 0; kh < 2; kh++) {                           \
    bf16x8 kf[4], vfr[4];                                                      \
    _Pragma("unroll") for (int ks = 0; ks < 4; ks++) {                         \
      int row = kh * 32 + l31;                                                 \
      int off = (ks * 32 + hi * 16) ^ ((row & 7) << 4);                        \
      kf[ks] = *(const bf16x8*)(kbp + (CUR)*8192 + row * 128 + off);           \
    }                                                                          \
    _Pragma("unroll") for (int sv = 0; sv < 2; sv++)                           \
        _Pragma("unroll") for (int hf = 0; hf < 2; hf++) {                     \
      int vrow = hf * 32 + l31;                                                \
      int voff = ((2 * kh + sv) * 32 + hi * 16) ^ ((vrow & 7) << 4);           \
      vfr[sv * 2 + hf] = *(const bf16x8*)(vbp + (CUR)*8192 + vrow * 128 + voff); \
    }                                                                          \
    f32x16 s;                                                                  \
    __builtin_amdgcn_s_setprio(1);                                             \
    _Pragma("unroll") for (int ks = 0; ks < 4; ks++)                           \
      s = __builtin_amdgcn_mfma_f32_32x32x16_bf16(kf[ks], qf[ks],              \
                                                  ks == 0 ? FZ : s, 0, 0, 0);  \
    __builtin_amdgcn_s_setprio(0);                                             \
    _Pragma("unroll") for (int r = 0; r < 16; r++)                             \
      s[r] = __builtin_amdgcn_exp2f(s[r]);                                     \
    lsum += (((s[0] + s[1]) + (s[2] + s[3])) + ((s[4] + s[5]) + (s[6] + s[7]))) + \
            (((s[8] + s[9]) + (s[10] + s[11])) + ((s[12] + s[13]) + (s[14] + s[15]))); \
    unsigned pk[8];                                                            \
    _Pragma("unroll") for (int i = 0; i < 8; i++)                              \
      asm("v_cvt_pk_bf16_f32 %0, %1, %2"                                       \
          : "=v"(pk[i]) : "v"(s[2 * i]), "v"(s[2 * i + 1]));                   \
    asm volatile("v_permlane32_swap_b32 %0, %1" : "+v"(pk[0]), "+v"(pk[2]));   \
    asm volatile("v_permlane32_swap_b32 %0, %1" : "+v"(pk[1]), "+v"(pk[3]));   \
    asm volatile("v_permlane32_swap_b32 %0, %1" : "+v"(pk[4]), "+v"(pk[6]));   \
    asm volatile("v_permlane32_swap_b32 %0, %1" : "+v"(pk[5]), "+v"(pk[7]));   \
    _Pragma("unroll") for (int sv = 0; sv < 2; sv++) {                         \
      union { bf16x8 v; unsigned u[4]; } fr;                                   \
      fr.u[0] = pk[sv * 4 + 0]; fr.u[1] = pk[sv * 4 + 1];                      \
      fr.u[2] = pk[sv * 4 + 2]; fr.u[3] = pk[sv * 4 + 3];                      \
      __builtin_amdgcn_s_setprio(1);                                           \
      oA[0] = __builtin_amdgcn_mfma_f32_32x32x16_bf16(fr.v, vfr[sv * 2 + 0], oA[0], 0, 0, 0); \
      oA[1] = __builtin_amdgcn_mfma_f32_32x32x16_bf16(fr.v, vfr[sv * 2 + 1], oA[1], 0, 0, 0); \
      __builtin_amdgcn_s_setprio(0);                                           \
    }                                                                          \
  }

__global__ __launch_bounds__(512, 4) void attn_kernel(
    const unsigned short* __restrict__ Q, const unsigned short* __restrict__ Kg,
    const unsigned short* __restrict__ V, unsigned short* __restrict__ XA) {
  __shared__ unsigned short Kt[2][2][64 * 64];  // [half][dbuf][m][hd] swizzled
  __shared__ unsigned short Vt[2][2][64 * 64];  // [half][dbuf][hd][m] swizzled
  int flat = blockIdx.x;
  int work = (flat & 7) * 64 + (flat >> 3);  // bijective XCD chunking
  int qb = work & 15, hbid = work >> 4;
  int h = hbid & 3, b = hbid >> 2;
  int tid = threadIdx.x, lane = tid & 63, w = tid >> 6;
  int qs = w & 3, half = w >> 2;
  int l31 = lane & 31, hi = lane >> 5;
  int q0 = qb * 128 + qs * 32;
  long hb = (long)b * HH + h;
  const unsigned short* Qb = Q + hb * NN * HD;
  const unsigned short* Kb = Kg + hb * NN * HD;
  const unsigned short* Vb = V + hb * HD * NN;
  const char* kbp = (const char*)&Kt[half][0][0];
  const char* vbp = (const char*)&Vt[half][0][0];

  const f32x16 FZ = {0.f, 0.f, 0.f, 0.f, 0.f, 0.f, 0.f, 0.f,
                     0.f, 0.f, 0.f, 0.f, 0.f, 0.f, 0.f, 0.f};

  // Q B-frags: row = q0 + (lane&31), k chunks of 8 at hi*8 within each 16
  bf16x8 qf[4];
#pragma unroll
  for (int ks = 0; ks < 4; ks++)
    qf[ks] = *(const bf16x8*)(Qb + (long)(q0 + l31) * HD + ks * 16 + hi * 8);

  f32x16 oA[2];
#pragma unroll
  for (int hf = 0; hf < 2; hf++)
#pragma unroll
    for (int r = 0; r < 16; r++) oA[hf][r] = 0.f;
  float lsum = 0.f;

  auto stage = [&](int buf, int t) {  // t = global tile index for this half
    int m0 = t * 64;
#pragma unroll
    for (int c = 0; c < 2; c++) {
      int row = qs * 16 + c * 8 + (lane >> 3);
      int so = ((lane & 7) * 16) ^ ((row & 7) << 4);
      gld16((const char*)Kb + (long)(m0 + row) * 128 + so,
            (char*)&Kt[half][buf][0] + (qs * 16 + c * 8) * 128);
      gld16((const char*)Vb + ((long)row * NN + m0) * 2 + so,
            (char*)&Vt[half][buf][0] + (qs * 16 + c * 8) * 128);
    }
  };

  const int HT = NN / 64 / 2;  // 16 tiles per half
  stage(0, half * HT);
  __syncthreads();

  for (int tt = 0; tt < HT; tt += 2) {
    if (tt + 1 < HT) stage(1, half * HT + tt + 1);
    ATTN_TILE(0);
    __syncthreads();
    if (tt + 2 < HT) stage(0, half * HT + tt + 2);
    ATTN_TILE(1);
    __syncthreads();
  }

  // ---- merge halves via LDS overlay (K/V buffers are dead now) ----
  float* mrgO = (float*)&Kt[0][0][0];  // 8192 floats = 32KB
  float* mrgL = (float*)&Vt[0][0][0];  // 256 floats
  if (half == 1) {
#pragma unroll
    for (int hf = 0; hf < 2; hf++)
#pragma unroll
      for (int r = 0; r < 16; r++)
        mrgO[qs * 2048 + hf * 1024 + r * 64 + lane] = oA[hf][r];
    mrgL[qs * 64 + lane] = lsum;
  }
  __syncthreads();
  if (half == 0) {
#pragma unroll
    for (int hf = 0; hf < 2; hf++)
#pragma unroll
      for (int r = 0; r < 16; r++)
        oA[hf][r] += mrgO[qs * 2048 + hf * 1024 + r * 64 + lane];
    lsum += mrgL[qs * 64 + lane];
    // finalize: l = own half-lane + partner (hi) half; normalize + write
    float lt = lsum + __shfl_xor(lsum, 32);
#pragma unroll
    for (int r = 0; r < 16; r++) {
      int qrow = (r & 3) + 8 * (r >> 2) + 4 * hi;  // C/D row for this reg
      float linv = 1.0f / __shfl(lt, qrow);
      long nrow = (long)b * NN + q0 + qrow;
#pragma unroll
      for (int hf = 0; hf < 2; hf++) {
        float val = oA[hf][r] * linv;
        XA[nrow * DD + h * HD + hf * 32 + l31] = f2bf(val);
      }
    }
  }
}

// ---- host launcher --------------------------------------------------------

extern "C" void kernel_launch(void* const* d_in, const int* in_sizes, int n_in,
                              void* d_out, int out_size, void* d_ws, size_t ws_size,
                              hipStream_t stream) {
  const float* q_in = (const float*)d_in[0];
  const float* k_in = (const float*)d_in[1];
  const float* v_in = (const float*)d_in[2];
  const float* Wq = (const float*)d_in[3];
  const float* bq = (const float*)d_in[4];
  const float* Wk = (const float*)d_in[5];
  const float* bk = (const float*)d_in[6];
  const float* Wv = (const float*)d_in[7];
  const float* bv = (const float*)d_in[8];
  const float* Wm = (const float*)d_in[9];
  const float* bm = (const float*)d_in[10];
  float* out = (float*)d_out;

  const long SX = (long)BB * NN * DD;
  const long SW = (long)DD * DD;
  unsigned short* Xqt = (unsigned short*)d_ws;
  unsigned short* Xkt = Xqt + SX;
  unsigned short* Xvt = Xkt + SX;
  unsigned short* Qh = Xvt + SX;
  unsigned short* Kh = Qh + SX;
  unsigned short* Vh = Kh + SX;
  unsigned short* Wqt = Vh + SX;
  unsigned short* Wkt = Wqt + SW;
  unsigned short* Wvt = Wkt + SW;
  unsigned short* Wmt = Wvt + SW;
  unsigned short* XAt = Xqt;  // Xqt dead after Q projection
  if (ws_size < (size_t)(6 * SX + 4 * SW) * 2) return;

  dim3 blk(256);
  tcast_x<<<dim3(NN / 64, DD / 64, 24), blk, 0, stream>>>(
      q_in, k_in, v_in, Xqt, Xkt, Xvt);
  tcast_w<<<dim3(DD / 32, DD / 32, 4), blk, 0, stream>>>(
      Wq, Wk, Wv, Wm, Wqt, Wkt, Wvt, Wmt);
  gemm_qkv<<<dim3(16, 4, 24), blk, 0, stream>>>(
      Xqt, Xkt, Xvt, Wqt, Wkt, Wvt, bq, bk, bv, Qh, Kh, Vh);
  attn_kernel<<<dim3(512), dim3(512), 0, stream>>>(Qh, Kh, Vh, XAt);
  gemm_out<<<dim3(16, 4, 8), blk, 0, stream>>>(Wmt, XAt, bm, out);
}